// Round 1
// 235.752 us; speedup vs baseline: 1.0044x; 1.0044x over previous
//
#include <hip/hip_runtime.h>

// Problem constants (match reference)
#define BB 4096
#define DD 8192
#define KK 5
#define GS 40
#define MAXIT 3
#define EFF 17              // 4*(KK-1)+1 composed taps
#define CHUNK 2048          // floats per block
#define C4 (CHUNK/4)        // 512 f4 per chunk
#define DF4 (DD/4)          // 2048 f4 per row
#define EPAD 20             // padded per-row composed-kernel stride (floats, 5 f4)
#define WS_OFF 64           // float offset of E table inside ws (keeps ws[0] free)

typedef float vf4 __attribute__((ext_vector_type(4)));

__device__ __forceinline__ int iabs(int a) { return a < 0 ? -a : a; }

// Compose e (length LEN) with a 5-tap kernel -> length LEN+4.
// LEN is a template parameter: every index is compile-time constant, so
// e[]/ne[] stay in VGPRs (no runtime-indexed-array scratch demotion).
template<int LEN>
__device__ __forceinline__ void compose5(float* e, const float* k5) {
    float ne[LEN + KK - 1];
#pragma unroll
    for (int m = 0; m < LEN + KK - 1; ++m) ne[m] = 0.f;
#pragma unroll
    for (int m = 0; m < LEN; ++m)
#pragma unroll
        for (int j = 0; j < KK; ++j) ne[m + j] += e[m] * k5[j];
#pragma unroll
    for (int m = 0; m < LEN + KK - 1; ++m) e[m] = ne[m];
}

__device__ __forceinline__ void pick5(int i, int iters, int max_it,
                                      const float* maxk, const float* idk,
                                      float* k5) {
#pragma unroll
    for (int j = 0; j < KK; ++j)
        k5[j] = (i < iters) ? maxk[j]
              : ((i < max_it) ? idk[j] : ((j == (KK - 1) / 2) ? 1.f : 0.f));
}

// ---------------------------------------------------------------------------
// Kernel A (16 blocks x 256): batch max + per-row composed 17-tap kernel.
// Each block independently reduces |g| over the whole batch (16 KB, L2-hot
// after the first block) -- removes the single-block k_max_it latency kernel
// and its serial dependency. Then each thread composes one row's effective
// kernel with fully compile-time-unrolled stages and writes 5 f4 to ws.
// ---------------------------------------------------------------------------
__global__ __launch_bounds__(256) void k_compose(const int* __restrict__ g,
                                                 const float* __restrict__ kernels,
                                                 float* __restrict__ wsE) {
    __shared__ int red[256];
    const int t = threadIdx.x;

    const int4* g4 = (const int4*)g;
    int m = 0;
    for (int i = t; i < BB / 4; i += 256) {
        int4 v = g4[i];
        m = max(m, max(max(iabs(v.x), iabs(v.y)), max(iabs(v.z), iabs(v.w))));
    }
    red[t] = m;
    __syncthreads();
    for (int s = 128; s > 0; s >>= 1) {
        if (t < s) red[t] = max(red[t], red[t + s]);
        __syncthreads();
    }
    const int max_it = red[0] / GS;

    const int r  = blockIdx.x * 256 + t;     // row, 16*256 = 4096
    const int gv = g[r];
    const int sign  = gv > 0 ? 1 : (gv < 0 ? -1 : 0);
    const int a     = iabs(gv);
    const int iters = a / GS;
    const int rem   = a % GS;

    const float* mk = kernels + (size_t)(sign * GS + GS) * KK;
    const float* ik = kernels + (size_t)GS * KK;
    const float* fk = kernels + (size_t)(rem * sign + GS) * KK;
    float maxk[KK], idk[KK], fink[KK];
#pragma unroll
    for (int j = 0; j < KK; ++j) { maxk[j] = mk[j]; idk[j] = ik[j]; fink[j] = fk[j]; }

    float e[EPAD];
#pragma unroll
    for (int q = 0; q < EPAD; ++q) e[q] = 0.f;
    e[0] = 1.f;

    float k5[KK];
    pick5(0, iters, max_it, maxk, idk, k5); compose5<1>(e, k5);
    pick5(1, iters, max_it, maxk, idk, k5); compose5<5>(e, k5);
    pick5(2, iters, max_it, maxk, idk, k5); compose5<9>(e, k5);
    compose5<13>(e, fink);                   // e[0..16] final, e[17..19] = 0

    vf4* dst = (vf4*)(wsE + (size_t)r * EPAD);
    vf4 o0; o0.x = e[0];  o0.y = e[1];  o0.z = e[2];  o0.w = e[3];
    vf4 o1; o1.x = e[4];  o1.y = e[5];  o1.z = e[6];  o1.w = e[7];
    vf4 o2; o2.x = e[8];  o2.y = e[9];  o2.z = e[10]; o2.w = e[11];
    vf4 o3; o3.x = e[12]; o3.y = e[13]; o3.z = e[14]; o3.w = e[15];
    vf4 o4; o4.x = e[16]; o4.y = e[17]; o4.z = e[18]; o4.w = e[19];
    dst[0] = o0; dst[1] = o1; dst[2] = o2; dst[3] = o3; dst[4] = o4;
}

// ---------------------------------------------------------------------------
// Kernel B: pure-stream conv. One block per 2048-float chunk (4 chunks/row).
// Stage coalesced f4 + halos to LDS, load this row's precomposed e[17]
// (5 uniform f4, L2-hot, overlaps staging latency), then 136 FMAs/thread
// from LDS with interleaved f4 assignment, NT f4 stores.
// ---------------------------------------------------------------------------
__global__ __launch_bounds__(256) void k_conv_pre(const float* __restrict__ x,
                                                  const float* __restrict__ wsE,
                                                  float* __restrict__ out) {
    __shared__ float lds[CHUNK + 16];        // [0..1] left halo f4, [2..513] chunk, [514..515] right halo
    float4* ldsv = (float4*)lds;

    const int bi   = blockIdx.x;
    const int b    = bi >> 2;                // row
    const int ch   = bi & 3;                 // chunk within row
    const int t    = threadIdx.x;
    const int c0f4 = ch * C4;

    const float4* xr = (const float4*)(x + (size_t)b * DD);

    ldsv[2 + t]       = xr[c0f4 + t];
    ldsv[2 + t + 256] = xr[c0f4 + t + 256];
    if (t == 0) {
        ldsv[0] = xr[(c0f4 - 2) & (DF4 - 1)];
        ldsv[1] = xr[(c0f4 - 1) & (DF4 - 1)];
    } else if (t == 1) {
        ldsv[514] = xr[(c0f4 + C4)     & (DF4 - 1)];
        ldsv[515] = xr[(c0f4 + C4 + 1) & (DF4 - 1)];
    }

    // uniform per-block: 5 f4 loads, broadcast via L1; issued pre-barrier
    const float4* ev = (const float4*)(wsE + (size_t)b * EPAD);
    float4 e0 = ev[0], e1 = ev[1], e2 = ev[2], e3 = ev[3], e4 = ev[4];
    float e[EFF] = { e0.x, e0.y, e0.z, e0.w,
                     e1.x, e1.y, e1.z, e1.w,
                     e2.x, e2.y, e2.z, e2.w,
                     e3.x, e3.y, e3.z, e3.w,
                     e4.x };

    __syncthreads();

    vf4* outr = (vf4*)(out + (size_t)b * DD);
#pragma unroll
    for (int jb = 0; jb < 2; ++jb) {
        const int v = jb * 256 + t;          // f4 idx within chunk [0,512)
        float f[EFF + 3];                    // x[d0-8 .. d0+11], d0 = 4v local
#pragma unroll
        for (int q = 0; q < 5; ++q) {
            float4 val = ldsv[v + q];        // halo shift: ldsv[2] == chunk start
            f[q * 4 + 0] = val.x; f[q * 4 + 1] = val.y;
            f[q * 4 + 2] = val.z; f[q * 4 + 3] = val.w;
        }
        float oc[4];
#pragma unroll
        for (int c = 0; c < 4; ++c) {
            float s = 0.f;
#pragma unroll
            for (int m = 0; m < EFF; ++m) s += e[m] * f[c + m];
            oc[c] = s;
        }
        vf4 o;
        o.x = oc[0]; o.y = oc[1]; o.z = oc[2]; o.w = oc[3];
        __builtin_nontemporal_store(o, outr + c0f4 + v);
    }
}

// ---------------------------------------------------------------------------
// Fallback path (ws too small): previous verified kernels, unchanged.
// ---------------------------------------------------------------------------
__global__ __launch_bounds__(256) void k_max_it(const int* __restrict__ g,
                                                int* __restrict__ ws) {
    __shared__ int red[256];
    int t = threadIdx.x;
    int m = 0;
    for (int i = t; i < BB; i += 256) m = max(m, iabs(g[i]));
    red[t] = m;
    __syncthreads();
    for (int s = 128; s > 0; s >>= 1) {
        if (t < s) red[t] = max(red[t], red[t + s]);
        __syncthreads();
    }
    if (t == 0) ws[0] = red[0] / GS;
}

__global__ __launch_bounds__(256) void k_conv(const float* __restrict__ x,
                                              const int* __restrict__ g,
                                              const float* __restrict__ kernels,
                                              const int* __restrict__ ws,
                                              float* __restrict__ out) {
    __shared__ float lds[CHUNK + 16];
    float4* ldsv = (float4*)lds;

    const int bi   = blockIdx.x;
    const int b    = bi >> 2;
    const int ch   = bi & 3;
    const int t    = threadIdx.x;
    const int c0f4 = ch * C4;

    const float4* xr = (const float4*)(x + (size_t)b * DD);

    ldsv[2 + t]       = xr[c0f4 + t];
    ldsv[2 + t + 256] = xr[c0f4 + t + 256];
    if (t == 0) {
        ldsv[0] = xr[(c0f4 - 2) & (DF4 - 1)];
        ldsv[1] = xr[(c0f4 - 1) & (DF4 - 1)];
    } else if (t == 1) {
        ldsv[514] = xr[(c0f4 + C4)     & (DF4 - 1)];
        ldsv[515] = xr[(c0f4 + C4 + 1) & (DF4 - 1)];
    }

    const int gv    = g[b];
    const int sign  = gv > 0 ? 1 : (gv < 0 ? -1 : 0);
    const int a     = iabs(gv);
    const int iters = a / GS;
    const int rem   = a % GS;
    const int max_it = ws[0];

    float maxk[KK], idk[KK], fink[KK];
    const float* mk = kernels + (size_t)(sign * GS + GS) * KK;
    const float* ik = kernels + (size_t)GS * KK;
    const float* fk = kernels + (size_t)(rem * sign + GS) * KK;
#pragma unroll
    for (int j = 0; j < KK; ++j) { maxk[j] = mk[j]; idk[j] = ik[j]; fink[j] = fk[j]; }

    float e[EPAD];
#pragma unroll
    for (int q = 0; q < EPAD; ++q) e[q] = 0.f;
    e[0] = 1.f;
    float k5[KK];
    pick5(0, iters, max_it, maxk, idk, k5); compose5<1>(e, k5);
    pick5(1, iters, max_it, maxk, idk, k5); compose5<5>(e, k5);
    pick5(2, iters, max_it, maxk, idk, k5); compose5<9>(e, k5);
    compose5<13>(e, fink);

    __syncthreads();

    vf4* outr = (vf4*)(out + (size_t)b * DD);
#pragma unroll
    for (int jb = 0; jb < 2; ++jb) {
        const int v = jb * 256 + t;
        float f[EFF + 3];
#pragma unroll
        for (int q = 0; q < 5; ++q) {
            float4 val = ldsv[v + q];
            f[q * 4 + 0] = val.x; f[q * 4 + 1] = val.y;
            f[q * 4 + 2] = val.z; f[q * 4 + 3] = val.w;
        }
        float oc[4];
#pragma unroll
        for (int c = 0; c < 4; ++c) {
            float s = 0.f;
#pragma unroll
            for (int m = 0; m < EFF; ++m) s += e[m] * f[c + m];
            oc[c] = s;
        }
        vf4 o;
        o.x = oc[0]; o.y = oc[1]; o.z = oc[2]; o.w = oc[3];
        __builtin_nontemporal_store(o, outr + c0f4 + v);
    }
}

// ---------------------------------------------------------------------------
extern "C" void kernel_launch(void* const* d_in, const int* in_sizes, int n_in,
                              void* d_out, int out_size, void* d_ws, size_t ws_size,
                              hipStream_t stream) {
    const float* x       = (const float*)d_in[0];
    const int*   g       = (const int*)d_in[1];
    const float* kernels = (const float*)d_in[2];
    float*       out     = (float*)d_out;

    const size_t need = (size_t)(WS_OFF + BB * EPAD) * sizeof(float);
    if (ws_size >= need) {
        float* wsE = (float*)d_ws + WS_OFF;
        k_compose<<<BB / 256, 256, 0, stream>>>(g, kernels, wsE);
        k_conv_pre<<<BB * (DD / CHUNK), 256, 0, stream>>>(x, wsE, out);
    } else {
        int* ws = (int*)d_ws;
        k_max_it<<<1, 256, 0, stream>>>(g, ws);
        k_conv<<<BB * (DD / CHUNK), 256, 0, stream>>>(x, g, kernels, ws, out);
    }
}